// Round 1
// baseline (285.943 us; speedup 1.0000x reference)
//
#include <hip/hip_runtime.h>
#include <math.h>

#define B_ 64
#define P_ 24564
#define G_ 48

// Workspace layout:
//   [0]  double              loss_sum
//   [8]  unsigned int        npos
//   [12] pad
//   [16] unsigned long long  bpk[B_*G_]   packed (iou_bits<<32 | ~p) best-prior keys

constexpr int GG  = 8;                     // gts per A-block
constexpr int NCH = 4;                     // prior chunks in A
constexpr int CHP = (P_ + NCH - 1) / NCH;  // 6141 (4*6141 == 24564 exactly)

__device__ __forceinline__ float iou_box(float gx1, float gy1, float gx2, float gy2, float ga,
                                         float px1, float py1, float px2, float py2, float pa) {
    float ix1 = fmaxf(gx1, px1), iy1 = fmaxf(gy1, py1);
    float ix2 = fminf(gx2, px2), iy2 = fminf(gy2, py2);
    float iw = fmaxf(ix2 - ix1, 0.0f), ih = fmaxf(iy2 - iy1, 0.0f);
    float inter = iw * ih;
    return inter / (ga + pa - inter);
}

// ---------------- Kernel A: best prior per (b, g)  (argmax over p, first-index ties) --------
__global__ __launch_bounds__(256) void best_prior_kernel(
    const float* __restrict__ priors, const float* __restrict__ gt,
    unsigned long long* __restrict__ bpk) {
    const int b  = blockIdx.z;
    const int g0 = blockIdx.y * GG;
    const int ch = blockIdx.x;

    float gx1[GG], gy1[GG], gx2[GG], gy2[GG], ga[GG];
#pragma unroll
    for (int i = 0; i < GG; i++) {
        const float* q = gt + ((size_t)b * G_ + g0 + i) * 5;
        gx1[i] = q[0]; gy1[i] = q[1]; gx2[i] = q[2]; gy2[i] = q[3];
        ga[i] = (q[2] - q[0]) * (q[3] - q[1]);
    }

    unsigned long long best[GG];
#pragma unroll
    for (int i = 0; i < GG; i++) best[i] = 0ull;

    const int pend = min(P_, (ch + 1) * CHP);
    for (int p = ch * CHP + (int)threadIdx.x; p < pend; p += 256) {
        float4 pr = ((const float4*)priors)[p];
        float px1 = pr.x - pr.z * 0.5f, py1 = pr.y - pr.w * 0.5f;
        float px2 = pr.x + pr.z * 0.5f, py2 = pr.y + pr.w * 0.5f;
        float pa = (px2 - px1) * (py2 - py1);
        unsigned long long lo = (unsigned long long)(0xFFFFFFFFu - (unsigned)p);
#pragma unroll
        for (int i = 0; i < GG; i++) {
            float v = iou_box(gx1[i], gy1[i], gx2[i], gy2[i], ga[i], px1, py1, px2, py2, pa);
            unsigned long long key = ((unsigned long long)__float_as_uint(v) << 32) | lo;
            if (key > best[i]) best[i] = key;
        }
    }

    // wave reduce, then cross-wave via LDS, then one atomicMax per g
    const int lane = threadIdx.x & 63, wv = threadIdx.x >> 6;
    __shared__ unsigned long long red[GG][4];
#pragma unroll
    for (int i = 0; i < GG; i++) {
        unsigned long long v = best[i];
        for (int off = 32; off; off >>= 1) {
            unsigned long long o = __shfl_down(v, off, 64);
            if (o > v) v = o;
        }
        if (lane == 0) red[i][wv] = v;
    }
    __syncthreads();
    if (threadIdx.x < GG) {
        unsigned long long v = red[threadIdx.x][0];
#pragma unroll
        for (int w = 1; w < 4; w++) v = max(v, red[threadIdx.x][w]);
        atomicMax(&bpk[(size_t)b * G_ + g0 + threadIdx.x], v);
    }
}

// ---------------- Kernel B: per-prior match + repulsion loss --------------------------------
__global__ __launch_bounds__(256) void loss_kernel(
    const float* __restrict__ pred_loc, const float* __restrict__ priors,
    const float* __restrict__ gt, const unsigned long long* __restrict__ bpk,
    double* __restrict__ loss_sum, unsigned int* __restrict__ nposp) {
    const int b = blockIdx.y;
    const int p = blockIdx.x * 256 + threadIdx.x;

    __shared__ float sx1[G_], sy1[G_], sx2[G_], sy2[G_], sa[G_], slb[G_];
    __shared__ int sbp[G_];
    if (threadIdx.x < G_) {
        const float* q = gt + ((size_t)b * G_ + threadIdx.x) * 5;
        float x1 = q[0], y1 = q[1], x2 = q[2], y2 = q[3];
        sx1[threadIdx.x] = x1; sy1[threadIdx.x] = y1;
        sx2[threadIdx.x] = x2; sy2[threadIdx.x] = y2;
        sa[threadIdx.x] = (x2 - x1) * (y2 - y1);
        slb[threadIdx.x] = q[4];
        sbp[threadIdx.x] =
            (int)(0xFFFFFFFFu - (unsigned)(bpk[(size_t)b * G_ + threadIdx.x] & 0xFFFFFFFFull));
    }
    __syncthreads();

    float contrib = 0.0f;
    unsigned int ispos = 0;
    if (p < P_) {
        float4 pr = ((const float4*)priors)[p];
        float px1 = pr.x - pr.z * 0.5f, py1 = pr.y - pr.w * 0.5f;
        float px2 = pr.x + pr.z * 0.5f, py2 = pr.y + pr.w * 0.5f;
        float pa = (px2 - px1) * (py2 - py1);

        float ov[G_];
#pragma unroll
        for (int g = 0; g < G_; g++)
            ov[g] = iou_box(sx1[g], sy1[g], sx2[g], sy2[g], sa[g], px1, py1, px2, py2, pa);

        // best gt per prior (first-index argmax)
        float bv = ov[0]; int bi = 0;
#pragma unroll
        for (int g = 1; g < G_; g++)
            if (ov[g] > bv) { bv = ov[g]; bi = g; }

        // scatter override: ascending g, last write wins (matches .at[].set order)
#pragma unroll
        for (int g = 0; g < G_; g++)
            if (sbp[g] == p) { bv = 2.0f; bi = g; }

        int conf = (int)slb[bi] + 1;
        if (bv < 0.5f) conf = 0;

        // repulsion gt: argmax over g excluding bi (value -1 there), first-index ties
        float rv = -2.0f; int ri = 0;
#pragma unroll
        for (int g = 0; g < G_; g++) {
            float v = (g == bi) ? -1.0f : ov[g];
            if (v > rv) { rv = v; ri = g; }
        }

        // decode predicted box
        float4 l = ((const float4*)pred_loc)[(size_t)b * P_ + p];
        float cx = pr.x + l.x * 0.1f * pr.z;
        float cy = pr.y + l.y * 0.1f * pr.w;
        float w  = pr.z * expf(l.z * 0.2f);
        float h  = pr.w * expf(l.w * 0.2f);
        float dx1 = cx - w * 0.5f, dy1 = cy - h * 0.5f;
        float dx2 = cx + w * 0.5f, dy2 = cy + h * 0.5f;

        // IOG(rep gt, decoded)
        float ix1 = fmaxf(sx1[ri], dx1), iy1 = fmaxf(sy1[ri], dy1);
        float ix2 = fminf(sx2[ri], dx2), iy2 = fminf(sy2[ri], dy2);
        float iw = fmaxf(ix2 - ix1, 0.0f), ih = fmaxf(iy2 - iy1, 0.0f);
        float inter = iw * ih;
        float iogv = inter / (sa[ri] + 1e-7f);

        if (conf > 0) {
            ispos = 1;
            if (iogv < 0.95f) {
                if (iogv < 0.5f)
                    contrib = -logf(1.0f - iogv + 1e-7f);
                else
                    contrib = (iogv - 0.5f) * 2.0f + 0.69314718055994531f;  // -ln(0.5)
            }
        }
    }

    // block reduction: wave shuffle + LDS + one double atomic per block
    for (int off = 32; off; off >>= 1) {
        contrib += __shfl_down(contrib, off, 64);
        ispos   += __shfl_down(ispos, off, 64);
    }
    __shared__ float rs[4];
    __shared__ unsigned int rn[4];
    const int lane = threadIdx.x & 63, wv = threadIdx.x >> 6;
    if (lane == 0) { rs[wv] = contrib; rn[wv] = ispos; }
    __syncthreads();
    if (threadIdx.x == 0) {
        float s = rs[0] + rs[1] + rs[2] + rs[3];
        unsigned int n = rn[0] + rn[1] + rn[2] + rn[3];
        if (s != 0.0f) atomicAdd(loss_sum, (double)s);
        if (n) atomicAdd(nposp, n);
    }
}

// ---------------- Kernel C: finalize ---------------------------------------------------------
__global__ void finalize_kernel(const double* __restrict__ loss_sum,
                                const unsigned int* __restrict__ nposp,
                                float* __restrict__ out) {
    out[0] = (float)(loss_sum[0] / (double)nposp[0]);
}

extern "C" void kernel_launch(void* const* d_in, const int* in_sizes, int n_in,
                              void* d_out, int out_size, void* d_ws, size_t ws_size,
                              hipStream_t stream) {
    const float* pred_loc = (const float*)d_in[0];  // [B,P,4]
    const float* priors   = (const float*)d_in[1];  // [P,4]
    const float* gt       = (const float*)d_in[2];  // [B,G,5]
    float* out = (float*)d_out;

    double* loss_sum = (double*)d_ws;
    unsigned int* nposp = (unsigned int*)((char*)d_ws + 8);
    unsigned long long* bpk = (unsigned long long*)((char*)d_ws + 16);

    hipMemsetAsync(d_ws, 0, 16 + (size_t)B_ * G_ * 8, stream);

    dim3 gridA(NCH, G_ / GG, B_);
    best_prior_kernel<<<gridA, 256, 0, stream>>>(priors, gt, bpk);

    dim3 gridB((P_ + 255) / 256, B_);
    loss_kernel<<<gridB, 256, 0, stream>>>(pred_loc, priors, gt, bpk, loss_sum, nposp);

    finalize_kernel<<<1, 1, 0, stream>>>(loss_sum, nposp, out);
}

// Round 2
// 262.913 us; speedup vs baseline: 1.0876x; 1.0876x over previous
//
#include <hip/hip_runtime.h>
#include <math.h>

#define B_ 64
#define P_ 24564
#define G_ 48

// Workspace layout:
//   [0]  double              loss_sum
//   [8]  unsigned int        npos
//   [12] pad
//   [16] unsigned long long  bpk[B_*G_]   packed (iou_bits<<32 | ~p) best-prior keys

constexpr int GG  = 8;                     // gts per A-block
constexpr int NCH = 4;                     // prior chunks in A
constexpr int CHP = (P_ + NCH - 1) / NCH;  // 6141 (4*6141 == 24564 exactly)

__device__ __forceinline__ float frcp(float x) { return __builtin_amdgcn_rcpf(x); }

// ---------------- Kernel A: best prior per (b, g)  (argmax over p, first-index ties) --------
__global__ __launch_bounds__(256) void best_prior_kernel(
    const float* __restrict__ priors, const float* __restrict__ gt,
    unsigned long long* __restrict__ bpk) {
    const int b  = blockIdx.z;
    const int g0 = blockIdx.y * GG;
    const int ch = blockIdx.x;

    float gx1[GG], gy1[GG], gx2[GG], gy2[GG], ga[GG];
#pragma unroll
    for (int i = 0; i < GG; i++) {
        const float* q = gt + ((size_t)b * G_ + g0 + i) * 5;
        gx1[i] = q[0]; gy1[i] = q[1]; gx2[i] = q[2]; gy2[i] = q[3];
        ga[i] = (q[2] - q[0]) * (q[3] - q[1]);
    }

    float bv[GG]; int bp[GG];
#pragma unroll
    for (int i = 0; i < GG; i++) { bv[i] = -1.0f; bp[i] = 0; }

    const int pend = min(P_, (ch + 1) * CHP);
    for (int p = ch * CHP + (int)threadIdx.x; p < pend; p += 256) {
        float4 pr = ((const float4*)priors)[p];
        float hx = pr.z * 0.5f, hy = pr.w * 0.5f;
        float px1 = pr.x - hx, py1 = pr.y - hy;
        float px2 = pr.x + hx, py2 = pr.y + hy;
        float pa = (px2 - px1) * (py2 - py1);
#pragma unroll
        for (int i = 0; i < GG; i++) {
            float ix1 = fmaxf(gx1[i], px1), iy1 = fmaxf(gy1[i], py1);
            float ix2 = fminf(gx2[i], px2), iy2 = fminf(gy2[i], py2);
            float iw = fmaxf(ix2 - ix1, 0.0f), ih = fmaxf(iy2 - iy1, 0.0f);
            float inter = iw * ih;
            float v = inter * frcp(ga[i] + pa - inter);
            // strict > with ascending p keeps lowest p on ties (within thread)
            if (v > bv[i]) { bv[i] = v; bp[i] = p; }
        }
    }

    // pack (iou_bits, ~p) so u64 max == (value, lowest-index) argmax, then reduce
    const int lane = threadIdx.x & 63, wv = threadIdx.x >> 6;
    __shared__ unsigned long long red[GG][4];
#pragma unroll
    for (int i = 0; i < GG; i++) {
        unsigned long long v = ((unsigned long long)__float_as_uint(bv[i]) << 32) |
                               (unsigned long long)(0xFFFFFFFFu - (unsigned)bp[i]);
        for (int off = 32; off; off >>= 1) {
            unsigned long long o = __shfl_down(v, off, 64);
            if (o > v) v = o;
        }
        if (lane == 0) red[i][wv] = v;
    }
    __syncthreads();
    if (threadIdx.x < GG) {
        unsigned long long v = red[threadIdx.x][0];
#pragma unroll
        for (int w = 1; w < 4; w++) v = max(v, red[threadIdx.x][w]);
        atomicMax(&bpk[(size_t)b * G_ + g0 + threadIdx.x], v);
    }
}

// ---------------- Kernel B: per-prior match + repulsion loss --------------------------------
__global__ __launch_bounds__(256) void loss_kernel(
    const float* __restrict__ pred_loc, const float* __restrict__ priors,
    const float* __restrict__ gt, const unsigned long long* __restrict__ bpk,
    double* __restrict__ loss_sum, unsigned int* __restrict__ nposp) {
    const int b = blockIdx.y;
    const int p = blockIdx.x * 256 + threadIdx.x;

    __shared__ float4 sbox[G_];                               // gt corners
    __shared__ int sbp[G_] __attribute__((aligned(16)));      // best prior per gt
    if (threadIdx.x < G_) {
        const float* q = gt + ((size_t)b * G_ + threadIdx.x) * 5;
        sbox[threadIdx.x] = make_float4(q[0], q[1], q[2], q[3]);
        sbp[threadIdx.x] =
            (int)(0xFFFFFFFFu - (unsigned)(bpk[(size_t)b * G_ + threadIdx.x] & 0xFFFFFFFFull));
    }
    __syncthreads();

    float contrib = 0.0f;
    unsigned int ispos = 0;
    if (p < P_) {
        float4 pr = ((const float4*)priors)[p];
        float hx = pr.z * 0.5f, hy = pr.w * 0.5f;
        float px1 = pr.x - hx, py1 = pr.y - hy;
        float px2 = pr.x + hx, py2 = pr.y + hy;
        float pa = (px2 - px1) * (py2 - py1);

        // single pass: top-2 (value, first-index) over g
        float v1 = -2.0f, v2 = -2.0f;
        int i1 = 0, i2 = 0;
#pragma unroll
        for (int g = 0; g < G_; g++) {
            float4 gb = sbox[g];
            float ga = (gb.z - gb.x) * (gb.w - gb.y);
            float ix1 = fmaxf(gb.x, px1), iy1 = fmaxf(gb.y, py1);
            float ix2 = fminf(gb.z, px2), iy2 = fminf(gb.w, py2);
            float iw = fmaxf(ix2 - ix1, 0.0f), ih = fmaxf(iy2 - iy1, 0.0f);
            float inter = iw * ih;
            float v = inter * frcp(ga + pa - inter);
            bool t = v > v1;
            bool u = v > v2;
            v2 = u ? (t ? v1 : v) : v2;
            i2 = u ? (t ? i1 : g) : i2;
            v1 = t ? v : v1;
            i1 = t ? g : i1;
        }

        // scatter override: ascending g, last write wins (matches .at[].set order)
        int bi = i1;
        bool ovr = false;
        const int4* sbp4 = (const int4*)sbp;
#pragma unroll
        for (int q = 0; q < G_ / 4; q++) {
            int4 s = sbp4[q];
            if (s.x == p) { bi = 4 * q + 0; ovr = true; }
            if (s.y == p) { bi = 4 * q + 1; ovr = true; }
            if (s.z == p) { bi = 4 * q + 2; ovr = true; }
            if (s.w == p) { bi = 4 * q + 3; ovr = true; }
        }

        // labels >= 0  =>  conf>0  <=>  bv >= THRESH (override forces bv=2.0)
        bool pos = ovr || (v1 >= 0.5f);
        // rep gt = argmax over g excluding bi (first-index ties)
        int ri = (bi == i1) ? i2 : i1;

        if (pos) {
            ispos = 1;
            // decode predicted box
            float4 l = ((const float4*)pred_loc)[(size_t)b * P_ + p];
            float cx = pr.x + l.x * 0.1f * pr.z;
            float cy = pr.y + l.y * 0.1f * pr.w;
            float w  = pr.z * expf(l.z * 0.2f);
            float h  = pr.w * expf(l.w * 0.2f);
            float dx1 = cx - w * 0.5f, dy1 = cy - h * 0.5f;
            float dx2 = cx + w * 0.5f, dy2 = cy + h * 0.5f;

            float4 rb = sbox[ri];
            float ra = (rb.z - rb.x) * (rb.w - rb.y);
            float ix1 = fmaxf(rb.x, dx1), iy1 = fmaxf(rb.y, dy1);
            float ix2 = fminf(rb.z, dx2), iy2 = fminf(rb.w, dy2);
            float iw = fmaxf(ix2 - ix1, 0.0f), ih = fmaxf(iy2 - iy1, 0.0f);
            float inter = iw * ih;
            float iogv = inter * frcp(ra + 1e-7f);

            if (iogv < 0.95f) {
                if (iogv < 0.5f)
                    contrib = -logf(1.0f - iogv + 1e-7f);
                else
                    contrib = (iogv - 0.5f) * 2.0f + 0.69314718055994531f;  // -ln(0.5)
            }
        }
    }

    // block reduction: wave shuffle + LDS + one double atomic per block
    for (int off = 32; off; off >>= 1) {
        contrib += __shfl_down(contrib, off, 64);
        ispos   += __shfl_down(ispos, off, 64);
    }
    __shared__ float rs[4];
    __shared__ unsigned int rn[4];
    const int lane = threadIdx.x & 63, wv = threadIdx.x >> 6;
    if (lane == 0) { rs[wv] = contrib; rn[wv] = ispos; }
    __syncthreads();
    if (threadIdx.x == 0) {
        float s = rs[0] + rs[1] + rs[2] + rs[3];
        unsigned int n = rn[0] + rn[1] + rn[2] + rn[3];
        if (s != 0.0f) atomicAdd(loss_sum, (double)s);
        if (n) atomicAdd(nposp, n);
    }
}

// ---------------- Kernel C: finalize ---------------------------------------------------------
__global__ void finalize_kernel(const double* __restrict__ loss_sum,
                                const unsigned int* __restrict__ nposp,
                                float* __restrict__ out) {
    out[0] = (float)(loss_sum[0] / (double)nposp[0]);
}

extern "C" void kernel_launch(void* const* d_in, const int* in_sizes, int n_in,
                              void* d_out, int out_size, void* d_ws, size_t ws_size,
                              hipStream_t stream) {
    const float* pred_loc = (const float*)d_in[0];  // [B,P,4]
    const float* priors   = (const float*)d_in[1];  // [P,4]
    const float* gt       = (const float*)d_in[2];  // [B,G,5]
    float* out = (float*)d_out;

    double* loss_sum = (double*)d_ws;
    unsigned int* nposp = (unsigned int*)((char*)d_ws + 8);
    unsigned long long* bpk = (unsigned long long*)((char*)d_ws + 16);

    hipMemsetAsync(d_ws, 0, 16 + (size_t)B_ * G_ * 8, stream);

    dim3 gridA(NCH, G_ / GG, B_);
    best_prior_kernel<<<gridA, 256, 0, stream>>>(priors, gt, bpk);

    dim3 gridB((P_ + 255) / 256, B_);
    loss_kernel<<<gridB, 256, 0, stream>>>(pred_loc, priors, gt, bpk, loss_sum, nposp);

    finalize_kernel<<<1, 1, 0, stream>>>(loss_sum, nposp, out);
}

// Round 3
// 185.466 us; speedup vs baseline: 1.5418x; 1.4176x over previous
//
#include <hip/hip_runtime.h>
#include <math.h>

#define B_ 64
#define P_ 24564
#define G_ 48

// Workspace layout:
//   [0]  double              loss_sum
//   [8]  unsigned int        npos
//   [12] pad
//   [16] unsigned long long  bpk[B_*G_]   packed (iou_bits<<32 | ~p) best-prior keys

constexpr int GG  = 8;                      // gts per A-block
constexpr int NCH = 16;                     // prior chunks in A
constexpr int CHP = 1536;                   // 16*1536 = 24576 >= P_
constexpr int TRIPA = CHP / 256;            // 6 fixed iterations
constexpr int PPT = 4;                      // priors per thread in B

__device__ __forceinline__ float frcp(float x) { return __builtin_amdgcn_rcpf(x); }

// ---------------- Kernel A: best prior per (b, g)  (argmax over p, first-index ties) --------
__global__ __launch_bounds__(256) void best_prior_kernel(
    const float* __restrict__ priors, const float* __restrict__ gt,
    unsigned long long* __restrict__ bpk) {
    const int b  = blockIdx.z;
    const int g0 = blockIdx.y * GG;
    const int ch = blockIdx.x;

    float gx1[GG], gy1[GG], gx2[GG], gy2[GG], ga[GG];
#pragma unroll
    for (int i = 0; i < GG; i++) {
        const float* q = gt + ((size_t)b * G_ + g0 + i) * 5;
        gx1[i] = q[0]; gy1[i] = q[1]; gx2[i] = q[2]; gy2[i] = q[3];
        ga[i] = (q[2] - q[0]) * (q[3] - q[1]);
    }

    float bv[GG]; int bp[GG];
#pragma unroll
    for (int i = 0; i < GG; i++) { bv[i] = -1.0f; bp[i] = 0; }

    const int base = ch * CHP + (int)threadIdx.x;
#pragma unroll
    for (int t = 0; t < TRIPA; t++) {
        const int p  = base + t * 256;
        const int pc = min(p, P_ - 1);
        float4 pr = ((const float4*)priors)[pc];
        float hx = pr.z * 0.5f, hy = pr.w * 0.5f;
        float px1 = pr.x - hx, py1 = pr.y - hy;
        float px2 = pr.x + hx, py2 = pr.y + hy;
        float pa = (px2 - px1) * (py2 - py1);
        const bool valid = p < P_;
#pragma unroll
        for (int i = 0; i < GG; i++) {
            float ix1 = fmaxf(gx1[i], px1), iy1 = fmaxf(gy1[i], py1);
            float ix2 = fminf(gx2[i], px2), iy2 = fminf(gy2[i], py2);
            float iw = fmaxf(ix2 - ix1, 0.0f), ih = fmaxf(iy2 - iy1, 0.0f);
            float inter = iw * ih;
            float v = inter * frcp(ga[i] + pa - inter);
            v = valid ? v : -1.0f;
            // strict > with ascending p keeps lowest p on ties (within thread)
            if (v > bv[i]) { bv[i] = v; bp[i] = p; }
        }
    }

    // pack (iou_bits, ~p) so u64 max == (value, lowest-index) argmax, then reduce
    const int lane = threadIdx.x & 63, wv = threadIdx.x >> 6;
    __shared__ unsigned long long red[GG][4];
#pragma unroll
    for (int i = 0; i < GG; i++) {
        unsigned long long v = ((unsigned long long)__float_as_uint(bv[i]) << 32) |
                               (unsigned long long)(0xFFFFFFFFu - (unsigned)bp[i]);
        for (int off = 32; off; off >>= 1) {
            unsigned long long o = __shfl_down(v, off, 64);
            if (o > v) v = o;
        }
        if (lane == 0) red[i][wv] = v;
    }
    __syncthreads();
    if (threadIdx.x < GG) {
        unsigned long long v = red[threadIdx.x][0];
#pragma unroll
        for (int w = 1; w < 4; w++) v = max(v, red[threadIdx.x][w]);
        atomicMax(&bpk[(size_t)b * G_ + g0 + threadIdx.x], v);
    }
}

// ---------------- Kernel B: per-prior match + repulsion loss, PPT priors/thread -------------
__global__ __launch_bounds__(256) void loss_kernel(
    const float* __restrict__ pred_loc, const float* __restrict__ priors,
    const float* __restrict__ gt, const unsigned long long* __restrict__ bpk,
    double* __restrict__ loss_sum, unsigned int* __restrict__ nposp) {
    const int b  = blockIdx.y;
    const int p0 = blockIdx.x * (256 * PPT) + threadIdx.x;

    __shared__ float4 sbox[G_];                               // gt corners
    __shared__ float  sga[G_];                                // gt areas
    __shared__ int    sbp[G_] __attribute__((aligned(16)));   // best prior per gt
    if (threadIdx.x < G_) {
        const float* q = gt + ((size_t)b * G_ + threadIdx.x) * 5;
        float x1 = q[0], y1 = q[1], x2 = q[2], y2 = q[3];
        sbox[threadIdx.x] = make_float4(x1, y1, x2, y2);
        sga[threadIdx.x]  = (x2 - x1) * (y2 - y1);
        sbp[threadIdx.x] =
            (int)(0xFFFFFFFFu - (unsigned)(bpk[(size_t)b * G_ + threadIdx.x] & 0xFFFFFFFFull));
    }
    __syncthreads();

    int   pidx[PPT];
    float px1[PPT], py1[PPT], px2[PPT], py2[PPT], pa[PPT];
    float v1[PPT], v2[PPT];
    int   i1[PPT], i2[PPT];
#pragma unroll
    for (int j = 0; j < PPT; j++) {
        pidx[j] = p0 + 256 * j;
        int pc = min(pidx[j], P_ - 1);
        float4 pr = ((const float4*)priors)[pc];
        float hx = pr.z * 0.5f, hy = pr.w * 0.5f;
        px1[j] = pr.x - hx; py1[j] = pr.y - hy;
        px2[j] = pr.x + hx; py2[j] = pr.y + hy;
        pa[j] = (px2[j] - px1[j]) * (py2[j] - py1[j]);
        v1[j] = -2.0f; v2[j] = -2.0f; i1[j] = 0; i2[j] = 0;
    }

    // main loop: one LDS read per g feeds PPT independent IoU/top-2 chains
#pragma unroll 8
    for (int g = 0; g < G_; g++) {
        float4 gb = sbox[g];
        float  ga = sga[g];
#pragma unroll
        for (int j = 0; j < PPT; j++) {
            float ix1 = fmaxf(gb.x, px1[j]), iy1 = fmaxf(gb.y, py1[j]);
            float ix2 = fminf(gb.z, px2[j]), iy2 = fminf(gb.w, py2[j]);
            float iw = fmaxf(ix2 - ix1, 0.0f), ih = fmaxf(iy2 - iy1, 0.0f);
            float inter = iw * ih;
            float v = inter * frcp(ga + pa[j] - inter);
            bool t = v > v1[j];
            bool u = v > v2[j];
            v2[j] = u ? (t ? v1[j] : v) : v2[j];
            i2[j] = u ? (t ? i1[j] : g) : i2[j];
            v1[j] = t ? v : v1[j];
            i1[j] = t ? g : i1[j];
        }
    }

    // scatter override: ascending g, last write wins (matches .at[].set order)
    int  bi[PPT];
    bool ovr[PPT];
#pragma unroll
    for (int j = 0; j < PPT; j++) { bi[j] = i1[j]; ovr[j] = false; }
    const int4* sbp4 = (const int4*)sbp;
#pragma unroll
    for (int q = 0; q < G_ / 4; q++) {
        int4 s = sbp4[q];
#pragma unroll
        for (int j = 0; j < PPT; j++) {
            if (s.x == pidx[j]) { bi[j] = 4 * q + 0; ovr[j] = true; }
            if (s.y == pidx[j]) { bi[j] = 4 * q + 1; ovr[j] = true; }
            if (s.z == pidx[j]) { bi[j] = 4 * q + 2; ovr[j] = true; }
            if (s.w == pidx[j]) { bi[j] = 4 * q + 3; ovr[j] = true; }
        }
    }

    float contrib = 0.0f;
    unsigned int ispos = 0;
#pragma unroll
    for (int j = 0; j < PPT; j++) {
        // labels >= 0 => conf>0 <=> bv >= THRESH (override forces bv=2.0)
        bool pos = (pidx[j] < P_) && (ovr[j] || (v1[j] >= 0.5f));
        if (!pos) continue;
        ispos++;
        int ri = (bi[j] == i1[j]) ? i2[j] : i1[j];

        // decode predicted box (reload prior: L1-hot)
        float4 pr = ((const float4*)priors)[pidx[j]];
        float4 l  = ((const float4*)pred_loc)[(size_t)b * P_ + pidx[j]];
        float cx = pr.x + l.x * 0.1f * pr.z;
        float cy = pr.y + l.y * 0.1f * pr.w;
        float w  = pr.z * expf(l.z * 0.2f);
        float h  = pr.w * expf(l.w * 0.2f);
        float dx1 = cx - w * 0.5f, dy1 = cy - h * 0.5f;
        float dx2 = cx + w * 0.5f, dy2 = cy + h * 0.5f;

        float4 rb = sbox[ri];
        float ix1 = fmaxf(rb.x, dx1), iy1 = fmaxf(rb.y, dy1);
        float ix2 = fminf(rb.z, dx2), iy2 = fminf(rb.w, dy2);
        float iw = fmaxf(ix2 - ix1, 0.0f), ih = fmaxf(iy2 - iy1, 0.0f);
        float inter = iw * ih;
        float iogv = inter * frcp(sga[ri] + 1e-7f);

        if (iogv < 0.95f) {
            if (iogv < 0.5f)
                contrib += -logf(1.0f - iogv + 1e-7f);
            else
                contrib += (iogv - 0.5f) * 2.0f + 0.69314718055994531f;  // -ln(0.5)
        }
    }

    // block reduction: wave shuffle + LDS + one double atomic per block
    for (int off = 32; off; off >>= 1) {
        contrib += __shfl_down(contrib, off, 64);
        ispos   += __shfl_down(ispos, off, 64);
    }
    __shared__ float rs[4];
    __shared__ unsigned int rn[4];
    const int lane = threadIdx.x & 63, wv = threadIdx.x >> 6;
    if (lane == 0) { rs[wv] = contrib; rn[wv] = ispos; }
    __syncthreads();
    if (threadIdx.x == 0) {
        float s = rs[0] + rs[1] + rs[2] + rs[3];
        unsigned int n = rn[0] + rn[1] + rn[2] + rn[3];
        if (s != 0.0f) atomicAdd(loss_sum, (double)s);
        if (n) atomicAdd(nposp, n);
    }
}

// ---------------- Kernel C: finalize ---------------------------------------------------------
__global__ void finalize_kernel(const double* __restrict__ loss_sum,
                                const unsigned int* __restrict__ nposp,
                                float* __restrict__ out) {
    out[0] = (float)(loss_sum[0] / (double)nposp[0]);
}

extern "C" void kernel_launch(void* const* d_in, const int* in_sizes, int n_in,
                              void* d_out, int out_size, void* d_ws, size_t ws_size,
                              hipStream_t stream) {
    const float* pred_loc = (const float*)d_in[0];  // [B,P,4]
    const float* priors   = (const float*)d_in[1];  // [P,4]
    const float* gt       = (const float*)d_in[2];  // [B,G,5]
    float* out = (float*)d_out;

    double* loss_sum = (double*)d_ws;
    unsigned int* nposp = (unsigned int*)((char*)d_ws + 8);
    unsigned long long* bpk = (unsigned long long*)((char*)d_ws + 16);

    hipMemsetAsync(d_ws, 0, 16 + (size_t)B_ * G_ * 8, stream);

    dim3 gridA(NCH, G_ / GG, B_);
    best_prior_kernel<<<gridA, 256, 0, stream>>>(priors, gt, bpk);

    dim3 gridB((P_ + 256 * PPT - 1) / (256 * PPT), B_);
    loss_kernel<<<gridB, 256, 0, stream>>>(pred_loc, priors, gt, bpk, loss_sum, nposp);

    finalize_kernel<<<1, 1, 0, stream>>>(loss_sum, nposp, out);
}